// Round 12
// baseline (128.794 us; speedup 1.0000x reference)
//
#include <hip/hip_runtime.h>

#define HW 4608
#define CC 128
#define H 48
#define W 96
#define S_WIN 1152
#define SCALE 0.08838834764831845f  // 1/sqrt(128)

typedef __attribute__((ext_vector_type(8))) short bf16x8;
typedef __attribute__((ext_vector_type(4))) float f32x4;

static __device__ inline short f2bf(float f) {
    unsigned u = __builtin_bit_cast(unsigned, f);
    unsigned r = (u + 0x7fff + ((u >> 16) & 1)) >> 16;   // RNE
    return (short)r;
}

// ============ merged prep: corr frags + qkv frags + ws zeroing ============
__global__ __launch_bounds__(256)
void prep_all(const float* __restrict__ Q, const float* __restrict__ K, const float* __restrict__ V,
              const float* __restrict__ f0, const float* __restrict__ f1,
              bf16x8* __restrict__ cfragA, bf16x8* __restrict__ cfragB,
              bf16x8* __restrict__ qfrag, bf16x8* __restrict__ kfrag, bf16x8* __restrict__ vfrag,
              float* __restrict__ wsf)
{
    __shared__ float vt[32][132];
    const int bx = blockIdx.x;
    const int t = threadIdx.x;

    if (bx < 1152) {
        int zi = bx * 256 + t;
        if (zi < 12 * HW) wsf[zi] = 0.f;
        // ---- corr prep ----
        const int pt = bx % 72;
        const int z  = bx / 72;
        const int tensor = z >> 3, b = (z >> 2) & 1, kc = z & 3;
        const float* src = (tensor ? f1 : f0) + (size_t)b * CC * HW + (size_t)kc * 32 * HW + pt * 64;
        {
            int ch = t >> 4;
            int c4 = (t & 15) * 4;
            *(float4*)&vt[ch][c4]      = *(const float4*)&src[(size_t)ch * HW + c4];
            *(float4*)&vt[ch + 16][c4] = *(const float4*)&src[(size_t)(ch + 16) * HW + c4];
        }
        __syncthreads();
        int Rloc = t >> 6, lane = t & 63;
        int R = pt * 4 + Rloc;
        bf16x8 v;
        #pragma unroll
        for (int j = 0; j < 8; ++j) v[j] = f2bf(vt[(lane >> 4) * 8 + j][Rloc * 16 + (lane & 15)]);
        (tensor ? cfragB : cfragA)[((size_t)(b * 288 + R) * 4 + kc) * 64 + lane] = v;
    } else {
        // ---- qkv prep ----
        const int bx2 = bx - 1152;
        const int R2 = bx2 % 36;
        const int z  = bx2 / 36;
        const int tensor = z >> 3, wb = z & 7;
        const int bb = wb >> 2, wi = wb & 3, si = wi >> 1, sj = wi & 1;
        const float* src = (tensor == 0 ? Q : (tensor == 1 ? K : V)) + (size_t)bb * HW * CC;
        {
            int row = t >> 3;
            int c16 = (t & 7) * 16;
            int qw = R2 * 32 + row;
            int rr = qw / 48, cc = qw - rr * 48;
            int y = (si * 24 + rr + 12) % 48;
            int x = (sj * 48 + cc + 24) % 96;
            const float* rp = src + ((size_t)y * 96 + x) * CC + c16;
            #pragma unroll
            for (int u = 0; u < 4; ++u)
                *(float4*)&vt[row][c16 + u * 4] = *(const float4*)&rp[u * 4];
        }
        __syncthreads();
        if (tensor < 2) {
            bf16x8* frag = tensor == 0 ? qfrag : kfrag;
            #pragma unroll
            for (int e2 = 0; e2 < 2; ++e2) {
                int e = t + e2 * 256;
                int Rloc = e >> 8, kc = (e >> 6) & 3, lane = e & 63;
                int R = R2 * 2 + Rloc;
                bf16x8 v;
                #pragma unroll
                for (int j = 0; j < 8; ++j)
                    v[j] = f2bf(vt[Rloc * 16 + (lane & 15)][kc * 32 + (lane >> 4) * 8 + j]);
                frag[((size_t)(wb * 72 + R) * 4 + kc) * 64 + lane] = v;
            }
        } else {
            #pragma unroll
            for (int e2 = 0; e2 < 2; ++e2) {
                int e = t + e2 * 256;
                int dB = e >> 6, lane = e & 63;
                bf16x8 v;
                #pragma unroll
                for (int j = 0; j < 8; ++j)
                    v[j] = f2bf(vt[(lane >> 4) * 8 + j][dB * 16 + (lane & 15)]);
                vfrag[((size_t)(wb * 8 + dB) * 36 + R2) * 64 + lane] = v;
            }
        }
    }
}

// ============ fused: window attention (0..575) + corr stats 2-kt blocks (576..1871) ============
__global__ __launch_bounds__(256)
void fused_ws(const bf16x8* __restrict__ qfrag, const bf16x8* __restrict__ kfrag,
              const bf16x8* __restrict__ vfrag, float* __restrict__ out,
              const bf16x8* __restrict__ cfragA, const bf16x8* __restrict__ cfragB,
              float* __restrict__ rowsum, float* __restrict__ colsum)
{
    __shared__ __align__(16) char smem[38144];
    const int bx = blockIdx.x;
    const int t = threadIdx.x, lane = t & 63, w = t >> 6;

    if (bx < 576) {
        // ================= window attention, 16-q-row tile, 4 waves (R6 winner) =================
        short* Psh = (short*)smem;                              // 36864 B
        unsigned char* codes = (unsigned char*)(smem + 36864);  // 1152 B
        float* rsum_sh = (float*)(smem + 38016);                // 64 B
        const int qt = bx % 72, wb = bx / 72;
        const int bb = wb >> 2, wi = wb & 3, si = wi >> 1, sj = wi & 1;

        if (t < 16) rsum_sh[t] = 0.f;
        for (int i = t; i < S_WIN; i += 256) {
            int r = i / 48, c = i - r * 48;
            codes[i] = (unsigned char)((si ? (r >= 12) : 0) | ((sj ? (c >= 24) : 0) << 1));
        }
        __syncthreads();

        bf16x8 qf[4];
        {
            const bf16x8* qb = qfrag + ((size_t)(wb * 72 + qt) * 4) * 64 + lane;
            #pragma unroll
            for (int kc = 0; kc < 4; ++kc) qf[kc] = qb[kc * 64];
        }
        const int qcode = codes[qt * 16 + (lane & 15)];
        char* Pb = (char*)Psh;
        float rsum = 0.f;

        for (int kt = 0; kt < 18; ++kt) {
            int Rk = w * 18 + kt;
            const bf16x8* kb = kfrag + ((size_t)(wb * 72 + Rk) * 4) * 64 + lane;
            bf16x8 kf[4];
            #pragma unroll
            for (int kc = 0; kc < 4; ++kc) kf[kc] = kb[kc * 64];
            int k0 = Rk * 16 + (lane >> 4) * 4;
            f32x4 acc = {0.f, 0.f, 0.f, 0.f};
            #pragma unroll
            for (int kc = 0; kc < 4; ++kc)
                acc = __builtin_amdgcn_mfma_f32_16x16x32_bf16(kf[kc], qf[kc], acc, 0, 0, 0);
            float ev[4];
            #pragma unroll
            for (int r = 0; r < 4; ++r) {
                ev[r] = (codes[k0 + r] == qcode) ? __expf(acc[r] * SCALE) : 0.f;
                rsum += ev[r];
            }
            unsigned lo = (unsigned)(unsigned short)f2bf(ev[0]) | ((unsigned)(unsigned short)f2bf(ev[1]) << 16);
            unsigned hi = (unsigned)(unsigned short)f2bf(ev[2]) | ((unsigned)(unsigned short)f2bf(ev[3]) << 16);
            int qloc = lane & 15;
            int off = (qloc * 2304 + k0 * 2) ^ ((qloc & 7) << 4);
            *(uint2*)(Pb + off) = make_uint2(lo, hi);
        }
        rsum += __shfl_xor(rsum, 16); rsum += __shfl_xor(rsum, 32);
        if (lane < 16) atomicAdd(&rsum_sh[lane], rsum);
        __syncthreads();

        f32x4 pv0 = {0.f, 0.f, 0.f, 0.f}, pv1 = {0.f, 0.f, 0.f, 0.f};
        const bf16x8* vb0 = vfrag + ((size_t)(wb * 8 + w) * 36) * 64 + lane;
        const bf16x8* vb1 = vfrag + ((size_t)(wb * 8 + w + 4) * 36) * 64 + lane;
        for (int kc = 0; kc < 36; ++kc) {
            int qloc = lane & 15;
            int off = (qloc * 2304 + kc * 64 + (lane >> 4) * 16) ^ ((qloc & 7) << 4);
            bf16x8 pf = *(const bf16x8*)(Pb + off);
            pv0 = __builtin_amdgcn_mfma_f32_16x16x32_bf16(pf, vb0[kc * 64], pv0, 0, 0, 0);
            pv1 = __builtin_amdgcn_mfma_f32_16x16x32_bf16(pf, vb1[kc * 64], pv1, 0, 0, 0);
        }
        #pragma unroll
        for (int r = 0; r < 4; ++r) {
            int qloc = (lane >> 4) * 4 + r;
            float rinv = 1.f / rsum_sh[qloc];
            int qw = qt * 16 + qloc;
            int rr = qw / 48, cc2 = qw - rr * 48;
            int y = (si * 24 + rr + 12) % 48;
            int x = (sj * 48 + cc2 + 24) % 96;
            float* op = &out[((size_t)bb * HW + y * 96 + x) * CC + (lane & 15)];
            op[w * 16]       = pv0[r] * rinv;
            op[(w + 4) * 16] = pv1[r] * rinv;
        }
    } else {
        // ===== corr pass A: 2 k-tiles per block; rowsum amortized across both =====
        float* rs = (float*)smem;             // [128]
        float* cs = (float*)(smem + 512);     // [256]
        const int bx2 = bx - 576;
        const int ktp = bx2 % 18, qt = (bx2 / 18) % 36, b = bx2 / 648;
        const int wm = w >> 1, wn = w & 1;

        const bf16x8* Ab = cfragA + (size_t)(b * 288 + qt * 8 + wm * 4) * 256 + lane;

        if (t < 128) rs[t] = 0.f;
        cs[t] = 0.f;
        __syncthreads();

        #pragma unroll
        for (int ktl = 0; ktl < 2; ++ktl) {
            int kt = ktp * 2 + ktl;
            const bf16x8* Bb = cfragB + (size_t)(b * 288 + kt * 8 + wn * 4) * 256 + lane;

            f32x4 acc[4][4] = {};
            #pragma unroll
            for (int kc = 0; kc < 4; ++kc) {
                bf16x8 a[4], bf[4];
                #pragma unroll
                for (int m = 0; m < 4; ++m) a[m]  = Ab[(m * 4 + kc) * 64];
                #pragma unroll
                for (int n = 0; n < 4; ++n) bf[n] = Bb[(n * 4 + kc) * 64];
                #pragma unroll
                for (int m = 0; m < 4; ++m)
                    #pragma unroll
                    for (int n = 0; n < 4; ++n)
                        acc[m][n] = __builtin_amdgcn_mfma_f32_16x16x32_bf16(a[m], bf[n], acc[m][n], 0, 0, 0);
            }

            float cv[4] = {};
            #pragma unroll
            for (int m = 0; m < 4; ++m) {
                float rv[4] = {};
                #pragma unroll
                for (int n = 0; n < 4; ++n)
                    #pragma unroll
                    for (int r = 0; r < 4; ++r) {
                        float ev = __expf(acc[m][n][r] * SCALE);
                        rv[r] += ev; cv[n] += ev;
                    }
                #pragma unroll
                for (int r = 0; r < 4; ++r) {
                    float s = rv[r];
                    s += __shfl_xor(s, 1); s += __shfl_xor(s, 2);
                    s += __shfl_xor(s, 4); s += __shfl_xor(s, 8);
                    if ((lane & 15) == 0)
                        atomicAdd(&rs[wm * 64 + m * 16 + (lane >> 4) * 4 + r], s);
                }
            }
            #pragma unroll
            for (int n = 0; n < 4; ++n) {
                float s = cv[n];
                s += __shfl_xor(s, 16); s += __shfl_xor(s, 32);
                if (lane < 16) atomicAdd(&cs[ktl * 128 + wn * 64 + n * 16 + lane], s);
            }
        }
        __syncthreads();
        if (t < 128) atomicAdd(&rowsum[(size_t)b * HW + qt * 128 + t], rs[t]);
        atomicAdd(&colsum[(size_t)b * HW + ktp * 256 + t], cs[t]);
    }
}

// ============ corr pass B: 2 k-tiles per block, per-m pipelined dual + flow ============
__global__ __launch_bounds__(256)
void corr_final(const bf16x8* __restrict__ fragA, const bf16x8* __restrict__ fragB,
                const float* __restrict__ rowsum, const float* __restrict__ colsum,
                float* __restrict__ rowflow, float* __restrict__ colflow,
                float* __restrict__ dual)
{
    __shared__ float sfx[128], sfy[128], scx[256], scy[256];
    __shared__ float stg[4][16][68];
    const int t = threadIdx.x, lane = t & 63, wave = t >> 6;
    const int wm = wave >> 1, wn = wave & 1;
    const int ktp = blockIdx.x, qt = blockIdx.y, b = blockIdx.z;

    const bf16x8* Ab = fragA + (size_t)(b * 288 + qt * 8 + wm * 4) * 256 + lane;

    if (t < 128) { sfx[t] = 0.f; sfy[t] = 0.f; }
    scx[t] = 0.f; scy[t] = 0.f;
    __syncthreads();

    const int qbase = qt * 128 + wm * 64;

    #pragma unroll
    for (int ktl = 0; ktl < 2; ++ktl) {
        const int kt = ktp * 2 + ktl;
        const bf16x8* Bb = fragB + (size_t)(b * 288 + kt * 8 + wn * 4) * 256 + lane;
        const int kbase = kt * 128 + wn * 64;

        float cinv[4], gkx[4], gky[4];
        #pragma unroll
        for (int n = 0; n < 4; ++n) {
            int k = kbase + n * 16 + (lane & 15);
            cinv[n] = 1.f / colsum[(size_t)b * HW + k];
            int kyi = k / W;
            gkx[n] = (float)(k - kyi * W); gky[n] = (float)kyi;
        }

        float cfx[4] = {}, cfy[4] = {};
        #pragma unroll
        for (int m = 0; m < 4; ++m) {
            f32x4 acc[4] = {};
            #pragma unroll
            for (int kc = 0; kc < 4; ++kc) {
                bf16x8 am = Ab[(m * 4 + kc) * 64];
                #pragma unroll
                for (int n = 0; n < 4; ++n)
                    acc[n] = __builtin_amdgcn_mfma_f32_16x16x32_bf16(am, Bb[(n * 4 + kc) * 64], acc[n], 0, 0, 0);
            }
            float rinv[4], gqx[4], gqy[4];
            int q0 = qbase + m * 16 + (lane >> 4) * 4;
            #pragma unroll
            for (int r = 0; r < 4; ++r) {
                rinv[r] = 1.f / rowsum[(size_t)b * HW + q0 + r];
                int qyi = (q0 + r) / W;
                gqx[r] = (float)(q0 + r - qyi * W); gqy[r] = (float)qyi;
            }
            float rfx[4] = {}, rfy[4] = {};
            #pragma unroll
            for (int n = 0; n < 4; ++n) {
                #pragma unroll
                for (int r = 0; r < 4; ++r) {
                    float ev = __expf(acc[n][r] * SCALE);
                    float rp = ev * rinv[r];
                    float ce = ev * cinv[n];
                    stg[wave][(lane >> 4) * 4 + r][n * 16 + (lane & 15)] = rp * ce;
                    rfx[r] += rp * gkx[n]; rfy[r] += rp * gky[n];
                    cfx[n] += ce * gqx[r]; cfy[n] += ce * gqy[r];
                }
            }
            #pragma unroll
            for (int pass = 0; pass < 4; ++pass) {
                int row = pass * 4 + (lane >> 4);
                f32x4 vv = *(const f32x4*)&stg[wave][row][(lane & 15) * 4];
                __builtin_nontemporal_store(vv,
                    (f32x4*)&dual[((size_t)b * HW + qbase + m * 16 + row) * HW + kbase + (lane & 15) * 4]);
            }
            #pragma unroll
            for (int r = 0; r < 4; ++r) {
                float sx = rfx[r], sy = rfy[r];
                sx += __shfl_xor(sx, 1); sx += __shfl_xor(sx, 2);
                sx += __shfl_xor(sx, 4); sx += __shfl_xor(sx, 8);
                sy += __shfl_xor(sy, 1); sy += __shfl_xor(sy, 2);
                sy += __shfl_xor(sy, 4); sy += __shfl_xor(sy, 8);
                if ((lane & 15) == 0) {
                    int row = wm * 64 + m * 16 + (lane >> 4) * 4 + r;
                    atomicAdd(&sfx[row], sx); atomicAdd(&sfy[row], sy);
                }
            }
        }
        #pragma unroll
        for (int n = 0; n < 4; ++n) {
            float sx = cfx[n], sy = cfy[n];
            sx += __shfl_xor(sx, 16); sx += __shfl_xor(sx, 32);
            sy += __shfl_xor(sy, 16); sy += __shfl_xor(sy, 32);
            if (lane < 16) {
                int col = ktl * 128 + wn * 64 + n * 16 + lane;
                atomicAdd(&scx[col], sx); atomicAdd(&scy[col], sy);
            }
        }
    }
    __syncthreads();
    if (t < 128) {
        atomicAdd(&rowflow[((size_t)b * HW + qt * 128 + t) * 2 + 0], sfx[t]);
        atomicAdd(&rowflow[((size_t)b * HW + qt * 128 + t) * 2 + 1], sfy[t]);
    }
    atomicAdd(&colflow[((size_t)b * HW + ktp * 256 + t) * 2 + 0], scx[t]);
    atomicAdd(&colflow[((size_t)b * HW + ktp * 256 + t) * 2 + 1], scy[t]);
}

// ============ flow finalize ============
__global__ void flow_finalize(const float* __restrict__ rowflow, const float* __restrict__ colflow,
                              float* __restrict__ out)
{
    int i = blockIdx.x * 256 + threadIdx.x;
    if (i >= 2 * 2 * HW) return;
    int bb   = i / (2 * HW);
    int rem  = i % (2 * HW);
    int chan = rem / HW;
    int q    = rem % HW;
    float g = (chan == 0) ? (float)(q % W) : (float)(q / W);
    out[i]              = rowflow[((size_t)bb * HW + q) * 2 + chan] - g;
    out[2 * 2 * HW + i] = colflow[((size_t)bb * HW + q) * 2 + chan] - g;
}

extern "C" void kernel_launch(void* const* d_in, const int* in_sizes, int n_in,
                              void* d_out, int out_size, void* d_ws, size_t ws_size,
                              hipStream_t stream)
{
    (void)in_sizes; (void)n_in; (void)out_size; (void)ws_size;
    const float* q  = (const float*)d_in[0];
    const float* k  = (const float*)d_in[1];
    const float* v  = (const float*)d_in[2];
    const float* f0 = (const float*)d_in[3];
    const float* f1 = (const float*)d_in[4];

    float* out = (float*)d_out;
    const size_t ATTN_SZ = (size_t)2 * HW * CC;
    const size_t FLOW_SZ = (size_t)2 * 2 * HW;
    float* f01  = out + ATTN_SZ;
    float* dual = out + ATTN_SZ + 2 * FLOW_SZ;

    const size_t FR = 2359296;
    char* wsb = (char*)d_ws;
    bf16x8* cfragA = (bf16x8*)(wsb);
    bf16x8* cfragB = (bf16x8*)(wsb + FR);
    bf16x8* qfrag  = (bf16x8*)(wsb + 2 * FR);
    bf16x8* kfrag  = (bf16x8*)(wsb + 3 * FR);
    bf16x8* vfrag  = (bf16x8*)(wsb + 4 * FR);
    float* wsf     = (float*)(wsb + 5 * FR);
    float* rowsum  = wsf;
    float* colsum  = wsf + 2 * HW;
    float* rowflow = wsf + 4 * HW;
    float* colflow = wsf + 8 * HW;

    prep_all<<<dim3(2016), 256, 0, stream>>>(q, k, v, f0, f1, cfragA, cfragB,
                                             qfrag, kfrag, vfrag, wsf);
    fused_ws<<<dim3(576 + 1296), 256, 0, stream>>>(qfrag, kfrag, vfrag, out,
                                                   cfragA, cfragB, rowsum, colsum);
    corr_final<<<dim3(18, 36, 2), 256, 0, stream>>>(cfragA, cfragB, rowsum, colsum,
                                                    rowflow, colflow, dual);
    flow_finalize<<<dim3(72), 256, 0, stream>>>(rowflow, colflow, f01);
}

// Round 13
// 118.110 us; speedup vs baseline: 1.0905x; 1.0905x over previous
//
#include <hip/hip_runtime.h>

#define HW 4608
#define CC 128
#define H 48
#define W 96
#define S_WIN 1152
#define SCALE 0.08838834764831845f  // 1/sqrt(128)

typedef __attribute__((ext_vector_type(8))) short bf16x8;
typedef __attribute__((ext_vector_type(4))) float f32x4;

static __device__ inline short f2bf(float f) {
    unsigned u = __builtin_bit_cast(unsigned, f);
    unsigned r = (u + 0x7fff + ((u >> 16) & 1)) >> 16;   // RNE
    return (short)r;
}

// ============ merged prep: corr frags + qkv frags + ws zeroing ============
__global__ __launch_bounds__(256)
void prep_all(const float* __restrict__ Q, const float* __restrict__ K, const float* __restrict__ V,
              const float* __restrict__ f0, const float* __restrict__ f1,
              bf16x8* __restrict__ cfragA, bf16x8* __restrict__ cfragB,
              bf16x8* __restrict__ qfrag, bf16x8* __restrict__ kfrag, bf16x8* __restrict__ vfrag,
              float* __restrict__ wsf)
{
    __shared__ float vt[32][132];
    const int bx = blockIdx.x;
    const int t = threadIdx.x;

    if (bx < 1152) {
        int zi = bx * 256 + t;
        if (zi < 12 * HW) wsf[zi] = 0.f;
        // ---- corr prep ----
        const int pt = bx % 72;
        const int z  = bx / 72;
        const int tensor = z >> 3, b = (z >> 2) & 1, kc = z & 3;
        const float* src = (tensor ? f1 : f0) + (size_t)b * CC * HW + (size_t)kc * 32 * HW + pt * 64;
        {
            int ch = t >> 4;
            int c4 = (t & 15) * 4;
            *(float4*)&vt[ch][c4]      = *(const float4*)&src[(size_t)ch * HW + c4];
            *(float4*)&vt[ch + 16][c4] = *(const float4*)&src[(size_t)(ch + 16) * HW + c4];
        }
        __syncthreads();
        int Rloc = t >> 6, lane = t & 63;
        int R = pt * 4 + Rloc;
        bf16x8 v;
        #pragma unroll
        for (int j = 0; j < 8; ++j) v[j] = f2bf(vt[(lane >> 4) * 8 + j][Rloc * 16 + (lane & 15)]);
        (tensor ? cfragB : cfragA)[((size_t)(b * 288 + R) * 4 + kc) * 64 + lane] = v;
    } else {
        // ---- qkv prep ----
        const int bx2 = bx - 1152;
        const int R2 = bx2 % 36;
        const int z  = bx2 / 36;
        const int tensor = z >> 3, wb = z & 7;
        const int bb = wb >> 2, wi = wb & 3, si = wi >> 1, sj = wi & 1;
        const float* src = (tensor == 0 ? Q : (tensor == 1 ? K : V)) + (size_t)bb * HW * CC;
        {
            int row = t >> 3;
            int c16 = (t & 7) * 16;
            int qw = R2 * 32 + row;
            int rr = qw / 48, cc = qw - rr * 48;
            int y = (si * 24 + rr + 12) % 48;
            int x = (sj * 48 + cc + 24) % 96;
            const float* rp = src + ((size_t)y * 96 + x) * CC + c16;
            #pragma unroll
            for (int u = 0; u < 4; ++u)
                *(float4*)&vt[row][c16 + u * 4] = *(const float4*)&rp[u * 4];
        }
        __syncthreads();
        if (tensor < 2) {
            bf16x8* frag = tensor == 0 ? qfrag : kfrag;
            #pragma unroll
            for (int e2 = 0; e2 < 2; ++e2) {
                int e = t + e2 * 256;
                int Rloc = e >> 8, kc = (e >> 6) & 3, lane = e & 63;
                int R = R2 * 2 + Rloc;
                bf16x8 v;
                #pragma unroll
                for (int j = 0; j < 8; ++j)
                    v[j] = f2bf(vt[Rloc * 16 + (lane & 15)][kc * 32 + (lane >> 4) * 8 + j]);
                frag[((size_t)(wb * 72 + R) * 4 + kc) * 64 + lane] = v;
            }
        } else {
            #pragma unroll
            for (int e2 = 0; e2 < 2; ++e2) {
                int e = t + e2 * 256;
                int dB = e >> 6, lane = e & 63;
                bf16x8 v;
                #pragma unroll
                for (int j = 0; j < 8; ++j)
                    v[j] = f2bf(vt[(lane >> 4) * 8 + j][dB * 16 + (lane & 15)]);
                vfrag[((size_t)(wb * 8 + dB) * 36 + R2) * 64 + lane] = v;
            }
        }
    }
}

// ============ fused: window attention w/ mask-tile skip (0..575) + corr stats (576..3167) ============
__global__ __launch_bounds__(256)
void fused_ws(const bf16x8* __restrict__ qfrag, const bf16x8* __restrict__ kfrag,
              const bf16x8* __restrict__ vfrag, float* __restrict__ out,
              const bf16x8* __restrict__ cfragA, const bf16x8* __restrict__ cfragB,
              float* __restrict__ rowsum, float* __restrict__ colsum)
{
    __shared__ __align__(16) char smem[38208];
    const int bx = blockIdx.x;
    const int t = threadIdx.x, lane = t & 63, w = t >> 6;

    if (bx < 576) {
        // ================= window attention, 16-q-row tile, 4 waves =================
        short* Psh = (short*)smem;                               // 36864 B
        unsigned char* codes = (unsigned char*)(smem + 36864);   // 1152 B
        float* rsum_sh = (float*)(smem + 38016);                 // 64 B
        unsigned char* pmask = (unsigned char*)(smem + 38080);   // 72 B: codes present per 16-pos tile
        const int qt = bx % 72, wb = bx / 72;
        const int bb = wb >> 2, wi = wb & 3, si = wi >> 1, sj = wi & 1;

        if (t < 16) rsum_sh[t] = 0.f;
        for (int i = t; i < S_WIN; i += 256) {
            int r = i / 48, c = i - r * 48;
            codes[i] = (unsigned char)((si ? (r >= 12) : 0) | ((sj ? (c >= 24) : 0) << 1));
        }
        __syncthreads();
        if (t < 72) {
            unsigned m = 0;
            #pragma unroll
            for (int j = 0; j < 16; ++j) m |= 1u << codes[t * 16 + j];
            pmask[t] = (unsigned char)m;
        }

        bf16x8 qf[4];
        {
            const bf16x8* qb = qfrag + ((size_t)(wb * 72 + qt) * 4) * 64 + lane;
            #pragma unroll
            for (int kc = 0; kc < 4; ++kc) qf[kc] = qb[kc * 64];
        }
        const int qcode = codes[qt * 16 + (lane & 15)];
        char* Pb = (char*)Psh;
        float rsum = 0.f;
        __syncthreads();
        const unsigned qpm = pmask[qt];

        // Phase 1: S^T = mfma(K, Q); skip fully-masked 16x16 tiles
        for (int kt = 0; kt < 18; ++kt) {
            int Rk = w * 18 + kt;
            int qloc = lane & 15;
            int k0 = Rk * 16 + (lane >> 4) * 4;
            int off = (qloc * 2304 + k0 * 2) ^ ((qloc & 7) << 4);
            if ((pmask[Rk] & qpm) == 0) {           // wave-uniform: whole tile masked -> P=0
                *(uint2*)(Pb + off) = make_uint2(0, 0);
                continue;
            }
            const bf16x8* kb = kfrag + ((size_t)(wb * 72 + Rk) * 4) * 64 + lane;
            bf16x8 kf[4];
            #pragma unroll
            for (int kc = 0; kc < 4; ++kc) kf[kc] = kb[kc * 64];
            f32x4 acc = {0.f, 0.f, 0.f, 0.f};
            #pragma unroll
            for (int kc = 0; kc < 4; ++kc)
                acc = __builtin_amdgcn_mfma_f32_16x16x32_bf16(kf[kc], qf[kc], acc, 0, 0, 0);
            float ev[4];
            #pragma unroll
            for (int r = 0; r < 4; ++r) {
                ev[r] = (codes[k0 + r] == qcode) ? __expf(acc[r] * SCALE) : 0.f;
                rsum += ev[r];
            }
            unsigned lo = (unsigned)(unsigned short)f2bf(ev[0]) | ((unsigned)(unsigned short)f2bf(ev[1]) << 16);
            unsigned hi = (unsigned)(unsigned short)f2bf(ev[2]) | ((unsigned)(unsigned short)f2bf(ev[3]) << 16);
            *(uint2*)(Pb + off) = make_uint2(lo, hi);
        }
        rsum += __shfl_xor(rsum, 16); rsum += __shfl_xor(rsum, 32);
        if (lane < 16) atomicAdd(&rsum_sh[lane], rsum);
        __syncthreads();

        // Phase 2: PV; skip 32-k slabs whose both tiles are masked
        f32x4 pv0 = {0.f, 0.f, 0.f, 0.f}, pv1 = {0.f, 0.f, 0.f, 0.f};
        const bf16x8* vb0 = vfrag + ((size_t)(wb * 8 + w) * 36) * 64 + lane;
        const bf16x8* vb1 = vfrag + ((size_t)(wb * 8 + w + 4) * 36) * 64 + lane;
        for (int kc = 0; kc < 36; ++kc) {
            if ((qpm & (unsigned)(pmask[2 * kc] | pmask[2 * kc + 1])) == 0) continue;
            int qloc = lane & 15;
            int off = (qloc * 2304 + kc * 64 + (lane >> 4) * 16) ^ ((qloc & 7) << 4);
            bf16x8 pf = *(const bf16x8*)(Pb + off);
            pv0 = __builtin_amdgcn_mfma_f32_16x16x32_bf16(pf, vb0[kc * 64], pv0, 0, 0, 0);
            pv1 = __builtin_amdgcn_mfma_f32_16x16x32_bf16(pf, vb1[kc * 64], pv1, 0, 0, 0);
        }
        #pragma unroll
        for (int r = 0; r < 4; ++r) {
            int qloc = (lane >> 4) * 4 + r;
            float rinv = 1.f / rsum_sh[qloc];
            int qw = qt * 16 + qloc;
            int rr = qw / 48, cc2 = qw - rr * 48;
            int y = (si * 24 + rr + 12) % 48;
            int x = (sj * 48 + cc2 + 24) % 96;
            float* op = &out[((size_t)bb * HW + y * 96 + x) * CC + (lane & 15)];
            op[w * 16]       = pv0[r] * rinv;
            op[(w + 4) * 16] = pv1[r] * rinv;
        }
    } else {
        // ================= corr pass A: row/col exp-sums =================
        float* rs = (float*)smem;
        float* cs = (float*)(smem + 512);
        const int bx2 = bx - 576;
        const int kt = bx2 % 36, qt = (bx2 / 36) % 36, b = bx2 / 1296;
        const int wm = w >> 1, wn = w & 1;

        const bf16x8* Ab = cfragA + (size_t)(b * 288 + qt * 8 + wm * 4) * 256 + lane;
        const bf16x8* Bb = cfragB + (size_t)(b * 288 + kt * 8 + wn * 4) * 256 + lane;

        f32x4 acc[4][4] = {};
        #pragma unroll
        for (int kc = 0; kc < 4; ++kc) {
            bf16x8 a[4], bf[4];
            #pragma unroll
            for (int m = 0; m < 4; ++m) a[m]  = Ab[(m * 4 + kc) * 64];
            #pragma unroll
            for (int n = 0; n < 4; ++n) bf[n] = Bb[(n * 4 + kc) * 64];
            #pragma unroll
            for (int m = 0; m < 4; ++m)
                #pragma unroll
                for (int n = 0; n < 4; ++n)
                    acc[m][n] = __builtin_amdgcn_mfma_f32_16x16x32_bf16(a[m], bf[n], acc[m][n], 0, 0, 0);
        }

        if (t < 128) { rs[t] = 0.f; cs[t] = 0.f; }
        __syncthreads();

        float cv[4] = {};
        #pragma unroll
        for (int m = 0; m < 4; ++m) {
            float rv[4] = {};
            #pragma unroll
            for (int n = 0; n < 4; ++n)
                #pragma unroll
                for (int r = 0; r < 4; ++r) {
                    float ev = __expf(acc[m][n][r] * SCALE);
                    rv[r] += ev; cv[n] += ev;
                }
            #pragma unroll
            for (int r = 0; r < 4; ++r) {
                float s = rv[r];
                s += __shfl_xor(s, 1); s += __shfl_xor(s, 2);
                s += __shfl_xor(s, 4); s += __shfl_xor(s, 8);
                if ((lane & 15) == 0)
                    atomicAdd(&rs[wm * 64 + m * 16 + (lane >> 4) * 4 + r], s);
            }
        }
        #pragma unroll
        for (int n = 0; n < 4; ++n) {
            float s = cv[n];
            s += __shfl_xor(s, 16); s += __shfl_xor(s, 32);
            if (lane < 16) atomicAdd(&cs[wn * 64 + n * 16 + lane], s);
        }
        __syncthreads();
        if (t < 128)      atomicAdd(&rowsum[(size_t)b * HW + qt * 128 + t], rs[t]);
        else              atomicAdd(&colsum[(size_t)b * HW + kt * 128 + (t - 128)], cs[t - 128]);
    }
}

// ============ corr pass B: dual_prob (nontemporal dwordx4 via LDS transpose) + flow ============
__global__ __launch_bounds__(256)
void corr_final(const bf16x8* __restrict__ fragA, const bf16x8* __restrict__ fragB,
                const float* __restrict__ rowsum, const float* __restrict__ colsum,
                float* __restrict__ rowflow, float* __restrict__ colflow,
                float* __restrict__ dual)
{
    __shared__ float sfx[128], sfy[128], scx[128], scy[128];
    __shared__ float stg[4][16][68];
    const int t = threadIdx.x, lane = t & 63, wave = t >> 6;
    const int wm = wave >> 1, wn = wave & 1;
    const int kt = blockIdx.x, qt = blockIdx.y, b = blockIdx.z;

    const bf16x8* Ab = fragA + (size_t)(b * 288 + qt * 8 + wm * 4) * 256 + lane;
    const bf16x8* Bb = fragB + (size_t)(b * 288 + kt * 8 + wn * 4) * 256 + lane;

    f32x4 acc[4][4] = {};
    #pragma unroll
    for (int kc = 0; kc < 4; ++kc) {
        bf16x8 a[4], bf[4];
        #pragma unroll
        for (int m = 0; m < 4; ++m) a[m]  = Ab[(m * 4 + kc) * 64];
        #pragma unroll
        for (int n = 0; n < 4; ++n) bf[n] = Bb[(n * 4 + kc) * 64];
        #pragma unroll
        for (int m = 0; m < 4; ++m)
            #pragma unroll
            for (int n = 0; n < 4; ++n)
                acc[m][n] = __builtin_amdgcn_mfma_f32_16x16x32_bf16(a[m], bf[n], acc[m][n], 0, 0, 0);
    }

    if (t < 128) { sfx[t] = 0.f; sfy[t] = 0.f; scx[t] = 0.f; scy[t] = 0.f; }
    __syncthreads();

    const int qbase = qt * 128 + wm * 64;
    const int kbase = kt * 128 + wn * 64;

    float cinv[4], gkx[4], gky[4];
    #pragma unroll
    for (int n = 0; n < 4; ++n) {
        int k = kbase + n * 16 + (lane & 15);
        cinv[n] = 1.f / colsum[(size_t)b * HW + k];
        int kyi = k / W;
        gkx[n] = (float)(k - kyi * W); gky[n] = (float)kyi;
    }

    float cfx[4] = {}, cfy[4] = {};
    #pragma unroll
    for (int m = 0; m < 4; ++m) {
        float rinv[4], gqx[4], gqy[4];
        int q0 = qbase + m * 16 + (lane >> 4) * 4;
        #pragma unroll
        for (int r = 0; r < 4; ++r) {
            rinv[r] = 1.f / rowsum[(size_t)b * HW + q0 + r];
            int qyi = (q0 + r) / W;
            gqx[r] = (float)(q0 + r - qyi * W); gqy[r] = (float)qyi;
        }
        float rfx[4] = {}, rfy[4] = {};
        #pragma unroll
        for (int n = 0; n < 4; ++n) {
            #pragma unroll
            for (int r = 0; r < 4; ++r) {
                float ev = __expf(acc[m][n][r] * SCALE);
                float rp = ev * rinv[r];
                float ce = ev * cinv[n];
                stg[wave][(lane >> 4) * 4 + r][n * 16 + (lane & 15)] = rp * ce;
                rfx[r] += rp * gkx[n]; rfy[r] += rp * gky[n];
                cfx[n] += ce * gqx[r]; cfy[n] += ce * gqy[r];
            }
        }
        #pragma unroll
        for (int pass = 0; pass < 4; ++pass) {
            int row = pass * 4 + (lane >> 4);
            f32x4 vv = *(const f32x4*)&stg[wave][row][(lane & 15) * 4];
            __builtin_nontemporal_store(vv,
                (f32x4*)&dual[((size_t)b * HW + qbase + m * 16 + row) * HW + kbase + (lane & 15) * 4]);
        }
        #pragma unroll
        for (int r = 0; r < 4; ++r) {
            float sx = rfx[r], sy = rfy[r];
            sx += __shfl_xor(sx, 1); sx += __shfl_xor(sx, 2);
            sx += __shfl_xor(sx, 4); sx += __shfl_xor(sx, 8);
            sy += __shfl_xor(sy, 1); sy += __shfl_xor(sy, 2);
            sy += __shfl_xor(sy, 4); sy += __shfl_xor(sy, 8);
            if ((lane & 15) == 0) {
                int row = wm * 64 + m * 16 + (lane >> 4) * 4 + r;
                atomicAdd(&sfx[row], sx); atomicAdd(&sfy[row], sy);
            }
        }
    }
    #pragma unroll
    for (int n = 0; n < 4; ++n) {
        float sx = cfx[n], sy = cfy[n];
        sx += __shfl_xor(sx, 16); sx += __shfl_xor(sx, 32);
        sy += __shfl_xor(sy, 16); sy += __shfl_xor(sy, 32);
        if (lane < 16) {
            int col = wn * 64 + n * 16 + lane;
            atomicAdd(&scx[col], sx); atomicAdd(&scy[col], sy);
        }
    }
    __syncthreads();
    if (t < 128) {
        atomicAdd(&rowflow[((size_t)b * HW + qt * 128 + t) * 2 + 0], sfx[t]);
        atomicAdd(&rowflow[((size_t)b * HW + qt * 128 + t) * 2 + 1], sfy[t]);
    } else {
        int j = t - 128;
        atomicAdd(&colflow[((size_t)b * HW + kt * 128 + j) * 2 + 0], scx[j]);
        atomicAdd(&colflow[((size_t)b * HW + kt * 128 + j) * 2 + 1], scy[j]);
    }
}

// ============ flow finalize ============
__global__ void flow_finalize(const float* __restrict__ rowflow, const float* __restrict__ colflow,
                              float* __restrict__ out)
{
    int i = blockIdx.x * 256 + threadIdx.x;
    if (i >= 2 * 2 * HW) return;
    int bb   = i / (2 * HW);
    int rem  = i % (2 * HW);
    int chan = rem / HW;
    int q    = rem % HW;
    float g = (chan == 0) ? (float)(q % W) : (float)(q / W);
    out[i]              = rowflow[((size_t)bb * HW + q) * 2 + chan] - g;
    out[2 * 2 * HW + i] = colflow[((size_t)bb * HW + q) * 2 + chan] - g;
}

extern "C" void kernel_launch(void* const* d_in, const int* in_sizes, int n_in,
                              void* d_out, int out_size, void* d_ws, size_t ws_size,
                              hipStream_t stream)
{
    (void)in_sizes; (void)n_in; (void)out_size; (void)ws_size;
    const float* q  = (const float*)d_in[0];
    const float* k  = (const float*)d_in[1];
    const float* v  = (const float*)d_in[2];
    const float* f0 = (const float*)d_in[3];
    const float* f1 = (const float*)d_in[4];

    float* out = (float*)d_out;
    const size_t ATTN_SZ = (size_t)2 * HW * CC;
    const size_t FLOW_SZ = (size_t)2 * 2 * HW;
    float* f01  = out + ATTN_SZ;
    float* dual = out + ATTN_SZ + 2 * FLOW_SZ;

    const size_t FR = 2359296;
    char* wsb = (char*)d_ws;
    bf16x8* cfragA = (bf16x8*)(wsb);
    bf16x8* cfragB = (bf16x8*)(wsb + FR);
    bf16x8* qfrag  = (bf16x8*)(wsb + 2 * FR);
    bf16x8* kfrag  = (bf16x8*)(wsb + 3 * FR);
    bf16x8* vfrag  = (bf16x8*)(wsb + 4 * FR);
    float* wsf     = (float*)(wsb + 5 * FR);
    float* rowsum  = wsf;
    float* colsum  = wsf + 2 * HW;
    float* rowflow = wsf + 4 * HW;
    float* colflow = wsf + 8 * HW;

    prep_all<<<dim3(2016), 256, 0, stream>>>(q, k, v, f0, f1, cfragA, cfragB,
                                             qfrag, kfrag, vfrag, wsf);
    fused_ws<<<dim3(576 + 2592), 256, 0, stream>>>(qfrag, kfrag, vfrag, out,
                                                   cfragA, cfragB, rowsum, colsum);
    corr_final<<<dim3(36, 36, 2), 256, 0, stream>>>(cfragA, cfragB, rowsum, colsum,
                                                    rowflow, colflow, dual);
    flow_finalize<<<dim3(72), 256, 0, stream>>>(rowflow, colflow, f01);
}

// Round 14
// 113.641 us; speedup vs baseline: 1.1333x; 1.0393x over previous
//
#include <hip/hip_runtime.h>

#define HW 4608
#define CC 128
#define H 48
#define W 96
#define S_WIN 1152
#define SCALE 0.08838834764831845f  // 1/sqrt(128)

typedef __attribute__((ext_vector_type(8))) short bf16x8;
typedef __attribute__((ext_vector_type(4))) float f32x4;

static __device__ inline short f2bf(float f) {
    unsigned u = __builtin_bit_cast(unsigned, f);
    unsigned r = (u + 0x7fff + ((u >> 16) & 1)) >> 16;   // RNE
    return (short)r;
}

// ============ merged prep: corr frags + qkv frags + ws zeroing ============
__global__ __launch_bounds__(256)
void prep_all(const float* __restrict__ Q, const float* __restrict__ K, const float* __restrict__ V,
              const float* __restrict__ f0, const float* __restrict__ f1,
              bf16x8* __restrict__ cfragA, bf16x8* __restrict__ cfragB,
              bf16x8* __restrict__ qfrag, bf16x8* __restrict__ kfrag, bf16x8* __restrict__ vfrag,
              float* __restrict__ wsf)
{
    __shared__ float vt[32][132];
    const int bx = blockIdx.x;
    const int t = threadIdx.x;

    if (bx < 1152) {
        int zi = bx * 256 + t;
        if (zi < 12 * HW) wsf[zi] = 0.f;
        // ---- corr prep ----
        const int pt = bx % 72;
        const int z  = bx / 72;
        const int tensor = z >> 3, b = (z >> 2) & 1, kc = z & 3;
        const float* src = (tensor ? f1 : f0) + (size_t)b * CC * HW + (size_t)kc * 32 * HW + pt * 64;
        {
            int ch = t >> 4;
            int c4 = (t & 15) * 4;
            *(float4*)&vt[ch][c4]      = *(const float4*)&src[(size_t)ch * HW + c4];
            *(float4*)&vt[ch + 16][c4] = *(const float4*)&src[(size_t)(ch + 16) * HW + c4];
        }
        __syncthreads();
        int Rloc = t >> 6, lane = t & 63;
        int R = pt * 4 + Rloc;
        bf16x8 v;
        #pragma unroll
        for (int j = 0; j < 8; ++j) v[j] = f2bf(vt[(lane >> 4) * 8 + j][Rloc * 16 + (lane & 15)]);
        (tensor ? cfragB : cfragA)[((size_t)(b * 288 + R) * 4 + kc) * 64 + lane] = v;
    } else {
        // ---- qkv prep ----
        const int bx2 = bx - 1152;
        const int R2 = bx2 % 36;
        const int z  = bx2 / 36;
        const int tensor = z >> 3, wb = z & 7;
        const int bb = wb >> 2, wi = wb & 3, si = wi >> 1, sj = wi & 1;
        const float* src = (tensor == 0 ? Q : (tensor == 1 ? K : V)) + (size_t)bb * HW * CC;
        {
            int row = t >> 3;
            int c16 = (t & 7) * 16;
            int qw = R2 * 32 + row;
            int rr = qw / 48, cc = qw - rr * 48;
            int y = (si * 24 + rr + 12) % 48;
            int x = (sj * 48 + cc + 24) % 96;
            const float* rp = src + ((size_t)y * 96 + x) * CC + c16;
            #pragma unroll
            for (int u = 0; u < 4; ++u)
                *(float4*)&vt[row][c16 + u * 4] = *(const float4*)&rp[u * 4];
        }
        __syncthreads();
        if (tensor < 2) {
            bf16x8* frag = tensor == 0 ? qfrag : kfrag;
            #pragma unroll
            for (int e2 = 0; e2 < 2; ++e2) {
                int e = t + e2 * 256;
                int Rloc = e >> 8, kc = (e >> 6) & 3, lane = e & 63;
                int R = R2 * 2 + Rloc;
                bf16x8 v;
                #pragma unroll
                for (int j = 0; j < 8; ++j)
                    v[j] = f2bf(vt[Rloc * 16 + (lane & 15)][kc * 32 + (lane >> 4) * 8 + j]);
                frag[((size_t)(wb * 72 + R) * 4 + kc) * 64 + lane] = v;
            }
        } else {
            #pragma unroll
            for (int e2 = 0; e2 < 2; ++e2) {
                int e = t + e2 * 256;
                int dB = e >> 6, lane = e & 63;
                bf16x8 v;
                #pragma unroll
                for (int j = 0; j < 8; ++j)
                    v[j] = f2bf(vt[(lane >> 4) * 8 + j][dB * 16 + (lane & 15)]);
                vfrag[((size_t)(wb * 8 + dB) * 36 + R2) * 64 + lane] = v;
            }
        }
    }
}

// ============ fused: window attention (blocks 0..575) + corr pass A (576..3167) ============
__global__ __launch_bounds__(256)
void fused_ws(const bf16x8* __restrict__ qfrag, const bf16x8* __restrict__ kfrag,
              const bf16x8* __restrict__ vfrag, float* __restrict__ out,
              const bf16x8* __restrict__ cfragA, const bf16x8* __restrict__ cfragB,
              float* __restrict__ rowsum, float* __restrict__ colsum)
{
    __shared__ __align__(16) char smem[38144];
    const int bx = blockIdx.x;
    const int t = threadIdx.x, lane = t & 63, w = t >> 6;

    if (bx < 576) {
        // ================= window attention, 16-q-row tile, 4 waves =================
        short* Psh = (short*)smem;                              // 36864 B
        unsigned char* codes = (unsigned char*)(smem + 36864);  // 1152 B
        float* rsum_sh = (float*)(smem + 38016);                // 64 B
        const int qt = bx % 72, wb = bx / 72;
        const int bb = wb >> 2, wi = wb & 3, si = wi >> 1, sj = wi & 1;

        if (t < 16) rsum_sh[t] = 0.f;
        for (int i = t; i < S_WIN; i += 256) {
            int r = i / 48, c = i - r * 48;
            codes[i] = (unsigned char)((si ? (r >= 12) : 0) | ((sj ? (c >= 24) : 0) << 1));
        }
        __syncthreads();

        bf16x8 qf[4];
        {
            const bf16x8* qb = qfrag + ((size_t)(wb * 72 + qt) * 4) * 64 + lane;
            #pragma unroll
            for (int kc = 0; kc < 4; ++kc) qf[kc] = qb[kc * 64];
        }
        const int qcode = codes[qt * 16 + (lane & 15)];
        char* Pb = (char*)Psh;
        float rsum = 0.f;

        // Phase 1: S^T = mfma(K, Q): col=q (lane&15), row=k. wave w covers Rk w*18..+18
        for (int kt = 0; kt < 18; ++kt) {
            int Rk = w * 18 + kt;
            const bf16x8* kb = kfrag + ((size_t)(wb * 72 + Rk) * 4) * 64 + lane;
            bf16x8 kf[4];
            #pragma unroll
            for (int kc = 0; kc < 4; ++kc) kf[kc] = kb[kc * 64];
            int k0 = Rk * 16 + (lane >> 4) * 4;
            f32x4 acc = {0.f, 0.f, 0.f, 0.f};
            #pragma unroll
            for (int kc = 0; kc < 4; ++kc)
                acc = __builtin_amdgcn_mfma_f32_16x16x32_bf16(kf[kc], qf[kc], acc, 0, 0, 0);
            float ev[4];
            #pragma unroll
            for (int r = 0; r < 4; ++r) {
                ev[r] = (codes[k0 + r] == qcode) ? __expf(acc[r] * SCALE) : 0.f;
                rsum += ev[r];
            }
            unsigned lo = (unsigned)(unsigned short)f2bf(ev[0]) | ((unsigned)(unsigned short)f2bf(ev[1]) << 16);
            unsigned hi = (unsigned)(unsigned short)f2bf(ev[2]) | ((unsigned)(unsigned short)f2bf(ev[3]) << 16);
            int qloc = lane & 15;
            int off = (qloc * 2304 + k0 * 2) ^ ((qloc & 7) << 4);
            *(uint2*)(Pb + off) = make_uint2(lo, hi);
        }
        rsum += __shfl_xor(rsum, 16); rsum += __shfl_xor(rsum, 32);
        if (lane < 16) atomicAdd(&rsum_sh[lane], rsum);
        __syncthreads();

        // Phase 2: PV. wave w owns d-slices w*16 and (w+4)*16
        f32x4 pv0 = {0.f, 0.f, 0.f, 0.f}, pv1 = {0.f, 0.f, 0.f, 0.f};
        const bf16x8* vb0 = vfrag + ((size_t)(wb * 8 + w) * 36) * 64 + lane;
        const bf16x8* vb1 = vfrag + ((size_t)(wb * 8 + w + 4) * 36) * 64 + lane;
        for (int kc = 0; kc < 36; ++kc) {
            int qloc = lane & 15;
            int off = (qloc * 2304 + kc * 64 + (lane >> 4) * 16) ^ ((qloc & 7) << 4);
            bf16x8 pf = *(const bf16x8*)(Pb + off);
            pv0 = __builtin_amdgcn_mfma_f32_16x16x32_bf16(pf, vb0[kc * 64], pv0, 0, 0, 0);
            pv1 = __builtin_amdgcn_mfma_f32_16x16x32_bf16(pf, vb1[kc * 64], pv1, 0, 0, 0);
        }
        #pragma unroll
        for (int r = 0; r < 4; ++r) {
            int qloc = (lane >> 4) * 4 + r;
            float rinv = 1.f / rsum_sh[qloc];
            int qw = qt * 16 + qloc;
            int rr = qw / 48, cc2 = qw - rr * 48;
            int y = (si * 24 + rr + 12) % 48;
            int x = (sj * 48 + cc2 + 24) % 96;
            float* op = &out[((size_t)bb * HW + y * 96 + x) * CC + (lane & 15)];
            op[w * 16]       = pv0[r] * rinv;
            op[(w + 4) * 16] = pv1[r] * rinv;
        }
    } else {
        // ================= corr pass A: row/col exp-sums =================
        float* rs = (float*)smem;
        float* cs = (float*)(smem + 512);
        const int bx2 = bx - 576;
        const int kt = bx2 % 36, qt = (bx2 / 36) % 36, b = bx2 / 1296;
        const int wm = w >> 1, wn = w & 1;

        const bf16x8* Ab = cfragA + (size_t)(b * 288 + qt * 8 + wm * 4) * 256 + lane;
        const bf16x8* Bb = cfragB + (size_t)(b * 288 + kt * 8 + wn * 4) * 256 + lane;

        f32x4 acc[4][4] = {};
        #pragma unroll
        for (int kc = 0; kc < 4; ++kc) {
            bf16x8 a[4], bf[4];
            #pragma unroll
            for (int m = 0; m < 4; ++m) a[m]  = Ab[(m * 4 + kc) * 64];
            #pragma unroll
            for (int n = 0; n < 4; ++n) bf[n] = Bb[(n * 4 + kc) * 64];
            #pragma unroll
            for (int m = 0; m < 4; ++m)
                #pragma unroll
                for (int n = 0; n < 4; ++n)
                    acc[m][n] = __builtin_amdgcn_mfma_f32_16x16x32_bf16(a[m], bf[n], acc[m][n], 0, 0, 0);
        }

        if (t < 128) { rs[t] = 0.f; cs[t] = 0.f; }
        __syncthreads();

        float cv[4] = {};
        #pragma unroll
        for (int m = 0; m < 4; ++m) {
            float rv[4] = {};
            #pragma unroll
            for (int n = 0; n < 4; ++n)
                #pragma unroll
                for (int r = 0; r < 4; ++r) {
                    float ev = __expf(acc[m][n][r] * SCALE);
                    rv[r] += ev; cv[n] += ev;
                }
            #pragma unroll
            for (int r = 0; r < 4; ++r) {
                float s = rv[r];
                s += __shfl_xor(s, 1); s += __shfl_xor(s, 2);
                s += __shfl_xor(s, 4); s += __shfl_xor(s, 8);
                if ((lane & 15) == 0)
                    atomicAdd(&rs[wm * 64 + m * 16 + (lane >> 4) * 4 + r], s);
            }
        }
        #pragma unroll
        for (int n = 0; n < 4; ++n) {
            float s = cv[n];
            s += __shfl_xor(s, 16); s += __shfl_xor(s, 32);
            if (lane < 16) atomicAdd(&cs[wn * 64 + n * 16 + lane], s);
        }
        __syncthreads();
        if (t < 128)      atomicAdd(&rowsum[(size_t)b * HW + qt * 128 + t], rs[t]);
        else              atomicAdd(&colsum[(size_t)b * HW + kt * 128 + (t - 128)], cs[t - 128]);
    }
}

// ============ corr pass B: dual_prob (nontemporal dwordx4 via LDS transpose) + flow ============
__global__ __launch_bounds__(256)
void corr_final(const bf16x8* __restrict__ fragA, const bf16x8* __restrict__ fragB,
                const float* __restrict__ rowsum, const float* __restrict__ colsum,
                float* __restrict__ rowflow, float* __restrict__ colflow,
                float* __restrict__ dual)
{
    __shared__ float sfx[128], sfy[128], scx[128], scy[128];
    __shared__ float stg[4][16][68];
    const int t = threadIdx.x, lane = t & 63, wave = t >> 6;
    const int wm = wave >> 1, wn = wave & 1;
    const int kt = blockIdx.x, qt = blockIdx.y, b = blockIdx.z;

    const bf16x8* Ab = fragA + (size_t)(b * 288 + qt * 8 + wm * 4) * 256 + lane;
    const bf16x8* Bb = fragB + (size_t)(b * 288 + kt * 8 + wn * 4) * 256 + lane;

    f32x4 acc[4][4] = {};
    #pragma unroll
    for (int kc = 0; kc < 4; ++kc) {
        bf16x8 a[4], bf[4];
        #pragma unroll
        for (int m = 0; m < 4; ++m) a[m]  = Ab[(m * 4 + kc) * 64];
        #pragma unroll
        for (int n = 0; n < 4; ++n) bf[n] = Bb[(n * 4 + kc) * 64];
        #pragma unroll
        for (int m = 0; m < 4; ++m)
            #pragma unroll
            for (int n = 0; n < 4; ++n)
                acc[m][n] = __builtin_amdgcn_mfma_f32_16x16x32_bf16(a[m], bf[n], acc[m][n], 0, 0, 0);
    }

    if (t < 128) { sfx[t] = 0.f; sfy[t] = 0.f; scx[t] = 0.f; scy[t] = 0.f; }
    __syncthreads();

    const int qbase = qt * 128 + wm * 64;
    const int kbase = kt * 128 + wn * 64;

    float cinv[4], gkx[4], gky[4];
    #pragma unroll
    for (int n = 0; n < 4; ++n) {
        int k = kbase + n * 16 + (lane & 15);
        cinv[n] = 1.f / colsum[(size_t)b * HW + k];
        int kyi = k / W;
        gkx[n] = (float)(k - kyi * W); gky[n] = (float)kyi;
    }

    float cfx[4] = {}, cfy[4] = {};
    #pragma unroll
    for (int m = 0; m < 4; ++m) {
        float rinv[4], gqx[4], gqy[4];
        int q0 = qbase + m * 16 + (lane >> 4) * 4;
        #pragma unroll
        for (int r = 0; r < 4; ++r) {
            rinv[r] = 1.f / rowsum[(size_t)b * HW + q0 + r];
            int qyi = (q0 + r) / W;
            gqx[r] = (float)(q0 + r - qyi * W); gqy[r] = (float)qyi;
        }
        float rfx[4] = {}, rfy[4] = {};
        #pragma unroll
        for (int n = 0; n < 4; ++n) {
            #pragma unroll
            for (int r = 0; r < 4; ++r) {
                float ev = __expf(acc[m][n][r] * SCALE);
                float rp = ev * rinv[r];
                float ce = ev * cinv[n];
                stg[wave][(lane >> 4) * 4 + r][n * 16 + (lane & 15)] = rp * ce;
                rfx[r] += rp * gkx[n]; rfy[r] += rp * gky[n];
                cfx[n] += ce * gqx[r]; cfy[n] += ce * gqy[r];
            }
        }
        #pragma unroll
        for (int pass = 0; pass < 4; ++pass) {
            int row = pass * 4 + (lane >> 4);
            f32x4 vv = *(const f32x4*)&stg[wave][row][(lane & 15) * 4];
            __builtin_nontemporal_store(vv,
                (f32x4*)&dual[((size_t)b * HW + qbase + m * 16 + row) * HW + kbase + (lane & 15) * 4]);
        }
        #pragma unroll
        for (int r = 0; r < 4; ++r) {
            float sx = rfx[r], sy = rfy[r];
            sx += __shfl_xor(sx, 1); sx += __shfl_xor(sx, 2);
            sx += __shfl_xor(sx, 4); sx += __shfl_xor(sx, 8);
            sy += __shfl_xor(sy, 1); sy += __shfl_xor(sy, 2);
            sy += __shfl_xor(sy, 4); sy += __shfl_xor(sy, 8);
            if ((lane & 15) == 0) {
                int row = wm * 64 + m * 16 + (lane >> 4) * 4 + r;
                atomicAdd(&sfx[row], sx); atomicAdd(&sfy[row], sy);
            }
        }
    }
    #pragma unroll
    for (int n = 0; n < 4; ++n) {
        float sx = cfx[n], sy = cfy[n];
        sx += __shfl_xor(sx, 16); sx += __shfl_xor(sx, 32);
        sy += __shfl_xor(sy, 16); sy += __shfl_xor(sy, 32);
        if (lane < 16) {
            int col = wn * 64 + n * 16 + lane;
            atomicAdd(&scx[col], sx); atomicAdd(&scy[col], sy);
        }
    }
    __syncthreads();
    if (t < 128) {
        atomicAdd(&rowflow[((size_t)b * HW + qt * 128 + t) * 2 + 0], sfx[t]);
        atomicAdd(&rowflow[((size_t)b * HW + qt * 128 + t) * 2 + 1], sfy[t]);
    } else {
        int j = t - 128;
        atomicAdd(&colflow[((size_t)b * HW + kt * 128 + j) * 2 + 0], scx[j]);
        atomicAdd(&colflow[((size_t)b * HW + kt * 128 + j) * 2 + 1], scy[j]);
    }
}

// ============ flow finalize ============
__global__ void flow_finalize(const float* __restrict__ rowflow, const float* __restrict__ colflow,
                              float* __restrict__ out)
{
    int i = blockIdx.x * 256 + threadIdx.x;
    if (i >= 2 * 2 * HW) return;
    int bb   = i / (2 * HW);
    int rem  = i % (2 * HW);
    int chan = rem / HW;
    int q    = rem % HW;
    float g = (chan == 0) ? (float)(q % W) : (float)(q / W);
    out[i]              = rowflow[((size_t)bb * HW + q) * 2 + chan] - g;
    out[2 * 2 * HW + i] = colflow[((size_t)bb * HW + q) * 2 + chan] - g;
}

extern "C" void kernel_launch(void* const* d_in, const int* in_sizes, int n_in,
                              void* d_out, int out_size, void* d_ws, size_t ws_size,
                              hipStream_t stream)
{
    (void)in_sizes; (void)n_in; (void)out_size; (void)ws_size;
    const float* q  = (const float*)d_in[0];
    const float* k  = (const float*)d_in[1];
    const float* v  = (const float*)d_in[2];
    const float* f0 = (const float*)d_in[3];
    const float* f1 = (const float*)d_in[4];

    float* out = (float*)d_out;
    const size_t ATTN_SZ = (size_t)2 * HW * CC;
    const size_t FLOW_SZ = (size_t)2 * 2 * HW;
    float* f01  = out + ATTN_SZ;
    float* dual = out + ATTN_SZ + 2 * FLOW_SZ;

    const size_t FR = 2359296;
    char* wsb = (char*)d_ws;
    bf16x8* cfragA = (bf16x8*)(wsb);
    bf16x8* cfragB = (bf16x8*)(wsb + FR);
    bf16x8* qfrag  = (bf16x8*)(wsb + 2 * FR);
    bf16x8* kfrag  = (bf16x8*)(wsb + 3 * FR);
    bf16x8* vfrag  = (bf16x8*)(wsb + 4 * FR);
    float* wsf     = (float*)(wsb + 5 * FR);
    float* rowsum  = wsf;
    float* colsum  = wsf + 2 * HW;
    float* rowflow = wsf + 4 * HW;
    float* colflow = wsf + 8 * HW;

    prep_all<<<dim3(2016), 256, 0, stream>>>(q, k, v, f0, f1, cfragA, cfragB,
                                             qfrag, kfrag, vfrag, wsf);
    fused_ws<<<dim3(576 + 2592), 256, 0, stream>>>(qfrag, kfrag, vfrag, out,
                                                   cfragA, cfragB, rowsum, colsum);
    corr_final<<<dim3(36, 36, 2), 256, 0, stream>>>(cfragA, cfragB, rowsum, colsum,
                                                    rowflow, colflow, dual);
    flow_finalize<<<dim3(72), 256, 0, stream>>>(rowflow, colflow, f01);
}